// Round 14
// baseline (2497.112 us; speedup 1.0000x reference)
//
#include <hip/hip_runtime.h>

#define BATCH 16
#define NPTS  2048
#define NMAT  32   // 16 batches x 2 preds
#define ITERS 20

typedef short bf16x8 __attribute__((ext_vector_type(8)));
typedef float f32x4 __attribute__((ext_vector_type(4)));
typedef unsigned short ushort_t;
typedef unsigned int uint_t;

// K = log2(e)/EPS, EPS = 0.05. Potentials pre-scaled: F = f*K (log2-domain).
// No LSE shift needed: terms 2^(pv - K*C) stay in fp32 range by ~80 bits.
constexpr float KSCALE = 28.853900817779268f;

__device__ __forceinline__ float fexp2(float x){ return __builtin_amdgcn_exp2f(x); }
__device__ __forceinline__ float flog2(float x){ return __builtin_amdgcn_logf(x); }
// sqrt(|x|): abs folds into v_sqrt_f32 as a free input modifier.
__device__ __forceinline__ float fsqrta(float x){ return __builtin_amdgcn_sqrtf(__builtin_fabsf(x)); }

__device__ __forceinline__ ushort_t bfr16(float x){
  uint_t u = __float_as_uint(x);
  return (ushort_t)((u + 0x7FFFu + ((u >> 16) & 1u)) >> 16);
}
__device__ __forceinline__ float bfrf(float x){
  return __uint_as_float(((uint_t)bfr16(x)) << 16);
}

// Per-point MFMA fragment encodings (27 used slots of K=32), bf16:
// per component c: L=[nh,nm,nl, 1,1,1, -2ah,-2ah,-2al], R=[1,1,1, nh,nm,nl, bh,bl,bh]
// sum_k L_k(p)*R_k(g) = |p|^2 + |g|^2 - 2(ah*bh+ah*bl+al*bh) ~= ||p-g||^2.
// Storage per cloud: 128 tiles x 1KB; lane l of tile t reads 16B at t*1024+l*16
// holding point (l&15)'s slots (l>>4)*8..+7 (A and B identical layout).
__device__ __forceinline__ void store_enc(ushort_t* base, int pt, const ushort_t* enc){
  ushort_t* p = base + (pt >> 4) * 512 + (pt & 15) * 8;
#pragma unroll
  for (int g = 0; g < 4; ++g){
    *reinterpret_cast<ushort4*>(p + g*128)     = make_ushort4(enc[g*8+0],enc[g*8+1],enc[g*8+2],enc[g*8+3]);
    *reinterpret_cast<ushort4*>(p + g*128 + 4) = make_ushort4(enc[g*8+4],enc[g*8+5],enc[g*8+6],enc[g*8+7]);
  }
}

__global__ void __launch_bounds__(256) pack_kernel(
    const float* __restrict__ gt, const float* __restrict__ p0, const float* __restrict__ p1,
    ushort_t* __restrict__ Lpred, ushort_t* __restrict__ Rpred,
    ushort_t* __restrict__ Lgt,   ushort_t* __restrict__ Rgt,
    float* __restrict__ emd, float* __restrict__ chamf)
{
  const int idx = blockIdx.x * 256 + threadIdx.x;
  const int totalPts = (NMAT + BATCH) * NPTS;
  if (idx < totalPts) {
    const int cl = idx >> 11, pt = idx & (NPTS - 1);
    const float* src; ushort_t *Lb, *Rb;
    if (cl < NMAT) {
      const int b = cl >> 1;
      src = ((cl & 1) ? p1 : p0) + (b * NPTS + pt) * 3;
      Lb = Lpred + cl * 65536; Rb = Rpred + cl * 65536;
    } else {
      const int b = cl - NMAT;
      src = gt + (b * NPTS + pt) * 3;
      Lb = Lgt + b * 65536; Rb = Rgt + b * 65536;
    }
    float L[32], R[32];
#pragma unroll
    for (int k = 27; k < 32; ++k){ L[k] = 0.f; R[k] = 0.f; }
#pragma unroll
    for (int c = 0; c < 3; ++c){
      const float v  = src[c];
      const float ah = bfrf(v), al = bfrf(v - ah);
      const float n2 = v * v;
      const float nh = bfrf(n2); const float r1 = n2 - nh;
      const float nm = bfrf(r1); const float nl = bfrf(r1 - nm);
      const int B0 = c * 9;
      L[B0+0]=nh;  L[B0+1]=nm;  L[B0+2]=nl;
      L[B0+3]=1.f; L[B0+4]=1.f; L[B0+5]=1.f;
      L[B0+6]=-2.f*ah; L[B0+7]=-2.f*ah; L[B0+8]=-2.f*al;
      R[B0+0]=1.f; R[B0+1]=1.f; R[B0+2]=1.f;
      R[B0+3]=nh;  R[B0+4]=nm;  R[B0+5]=nl;
      R[B0+6]=ah;  R[B0+7]=al;  R[B0+8]=ah;
    }
    ushort_t Le[32], Re[32];
#pragma unroll
    for (int k = 0; k < 32; ++k){ Le[k] = bfr16(L[k]); Re[k] = bfr16(R[k]); }
    store_enc(Lb, pt, Le);
    store_enc(Rb, pt, Re);
  } else if (idx == totalPts) {
    emd[0] = 0.f;
  } else if (idx == totalPts + 1) {
    chamf[0] = 0.f;
  }
}

// One Sinkhorn half-update over all 32 matrices via MFMA distance tiles.
// Grid = NMAT*32 (XCD-swizzled); block = 512 thr = 8 waves; block = 64 rows x 2048 cols.
// NF = A-fragments per wave. Wave holds NF*16 rows x (2048*16/(NF*16*8)) cols:
//   NF=4: 64 rows x 256 cols (8 col-splits)  -> B-traffic/CU = 0.5 MB
//   NF=2: 32 rows x 512 cols (2 row x 4 col) -> B-traffic/CU = 1 MB (CHAM/COST,
//         which need extra accumulator sets and would spill at NF=4)
// Same MFMA/trans count either way; only B-load redundancy changes.
// Potentials in group-of-4 layout: pot[(t>>2)*64 + c*4 + (t&3)], point i=t*16+c.
// COST=1 (final g-update): T_j = sum_i 2^(F_i-K*C)*C fused; emd += 2^(G_j)*T_j.
template<int CHAM, int RPOT, int GSIDE, int COST, int NF>
__global__ void __launch_bounds__(512, 8) sink_kernel(
    const ushort_t* __restrict__ Lpred, const ushort_t* __restrict__ Rpred,
    const ushort_t* __restrict__ Lgt,   const ushort_t* __restrict__ Rgt,
    float* __restrict__ FT, float* __restrict__ GT,
    float* __restrict__ chamf, float* __restrict__ emd)
{
  constexpr int RWR  = NF * 16;        // rows per wave
  constexpr int RS   = 64 / RWR;       // row splits (1 or 2)
  constexpr int WCOL = 8 / RS;         // col splits (8 or 4)
  constexpr int G4N  = 2048 / WCOL / 64; // 4-tile groups per wave (4 or 8)

  // XCD-aware swizzle: each XCD gets a contiguous logical range (1024%8==0)
  const int bx0 = blockIdx.x;
  const int bx  = (bx0 & 7) * (NMAT * 32 / 8) + (bx0 >> 3);
  const int m   = bx >> 5;
  const int rg5 = bx & 31;
  const int b   = m >> 1;
  const int tid = threadIdx.x;
  const int l   = tid & 63;
  const int w   = __builtin_amdgcn_readfirstlane(tid >> 6);
  const int wr  = w / WCOL;
  const int wc  = w % WCOL;

  const ushort_t* A  = GSIDE ? (Lgt + b*65536)   : (Lpred + m*65536);
  const ushort_t* Bm = GSIDE ? (Rpred + m*65536) : (Rgt + b*65536);
  const float* pinT  = (GSIDE ? FT : GT) + m*NPTS;
  float*       poutT = (GSIDE ? GT : FT) + m*NPTS;

  __shared__ float ssum[8][64];
  __shared__ float sdm[8][64];   // chamfer mins OR cost T sums (never both)

  // A fragments: rows rg5*64 + wr*RWR + q*16 .. +15
  bf16x8 af[NF];
#pragma unroll
  for (int q = 0; q < NF; ++q)
    af[q] = *reinterpret_cast<const bf16x8*>(A + (rg5*4 + wr*NF + q)*512 + l*8);

  float s[NF][4], dmn[NF][4], t[NF][4];
#pragma unroll
  for (int q = 0; q < NF; ++q)
#pragma unroll
    for (int r = 0; r < 4; ++r){ s[q][r]=0.f; dmn[q][r]=1e30f; t[q][r]=0.f; }

  const f32x4 zz = {0.f,0.f,0.f,0.f};
  const ushort_t* Bu = Bm + wc * (G4N*4) * 512;   // wave-uniform base
  const int voff = l * 8;
  const float* PTu = pinT + (wc*G4N)*64 + (l & 15)*4;

#pragma unroll 2
  for (int g4 = 0; g4 < G4N; ++g4) {
    const ushort_t* Bg = Bu + g4 * 2048;
    float cpv[4];
    if (RPOT) {
      const float4 cp = *reinterpret_cast<const float4*>(PTu + g4*64);
      cpv[0]=cp.x; cpv[1]=cp.y; cpv[2]=cp.z; cpv[3]=cp.w;
    } else {
      cpv[0]=0.f; cpv[1]=0.f; cpv[2]=0.f; cpv[3]=0.f;
    }
#pragma unroll
    for (int tt = 0; tt < 4; ++tt) {
      const bf16x8 bf = *reinterpret_cast<const bf16x8*>(Bg + voff + tt*512);
      const float pv = cpv[tt];
#pragma unroll
      for (int q = 0; q < NF; ++q) {
        f32x4 d4 = __builtin_amdgcn_mfma_f32_16x16x32_bf16(af[q], bf, zz, 0, 0, 0);
#pragma unroll
        for (int r = 0; r < 4; ++r) {
          if (CHAM) dmn[q][r] = fminf(dmn[q][r], d4[r]);
          const float C = fsqrta(d4[r]);
          const float e = RPOT ? fmaf(-KSCALE, C, pv) : (-KSCALE * C);
          const float x = fexp2(e);
          s[q][r] += x;
          if (COST) t[q][r] = fmaf(x, C, t[q][r]);
        }
      }
    }
  }

  // reduce across the 16 col-lanes sharing each row
#pragma unroll
  for (int o = 1; o < 16; o <<= 1) {
#pragma unroll
    for (int q = 0; q < NF; ++q)
#pragma unroll
      for (int r = 0; r < 4; ++r) {
        s[q][r] += __shfl_xor(s[q][r], o);
        if (CHAM) dmn[q][r] = fminf(dmn[q][r], __shfl_xor(dmn[q][r], o));
        if (COST) t[q][r] += __shfl_xor(t[q][r], o);
      }
  }
  if ((l & 15) == 0) {
    const int g = l >> 4;
#pragma unroll
    for (int q = 0; q < NF; ++q)
#pragma unroll
      for (int r = 0; r < 4; ++r) {
        ssum[w][q*16 + g*4 + r] = s[q][r];
        if (CHAM) sdm[w][q*16 + g*4 + r] = dmn[q][r];
        if (COST) sdm[w][q*16 + g*4 + r] = t[q][r];
      }
  }
  __syncthreads();

  // wave 0: 64 lanes = 64 rows; combine col-split waves, finalize
  if (tid < 64) {
    const int wrr = tid / RWR;
    const int lr  = tid % RWR;
    float S = 0.f;
#pragma unroll
    for (int k = 0; k < WCOL; ++k) S += ssum[wrr*WCOL + k][lr];
    const float val = -11.0f - flog2(S);
    poutT[rg5*64 + (tid & 15)*4 + (tid >> 4)] = val;
    if (CHAM) {
      float dm = 1e30f;
#pragma unroll
      for (int k = 0; k < WCOL; ++k) dm = fminf(dm, sdm[wrr*WCOL + k][lr]);
#pragma unroll
      for (int o = 1; o < 64; o <<= 1) dm += __shfl_xor(dm, o);
      if (tid == 0) atomicAdd(chamf, dm);
    }
    if (COST) {
      float Ts = 0.f;
#pragma unroll
      for (int k = 0; k < WCOL; ++k) Ts += sdm[wrr*WCOL + k][lr];
      float cj = fexp2(val) * Ts;
#pragma unroll
      for (int o = 1; o < 64; o <<= 1) cj += __shfl_xor(cj, o);
      if (tid == 0) atomicAdd(emd, cj);
    }
  }
}

__global__ void final_kernel(const float* __restrict__ emd,
                             const float* __restrict__ chamf,
                             float* __restrict__ out)
{
  if (blockIdx.x == 0 && threadIdx.x == 0) {
    out[0] = chamf[0] / (float)(BATCH * NPTS) + emd[0] / (float)BATCH;
  }
}

extern "C" void kernel_launch(void* const* d_in, const int* in_sizes, int n_in,
                              void* d_out, int out_size, void* d_ws, size_t ws_size,
                              hipStream_t stream) {
  (void)in_sizes; (void)n_in; (void)out_size; (void)ws_size;
  const float* gt = (const float*)d_in[0];
  const float* p0 = (const float*)d_in[2];
  const float* p1 = (const float*)d_in[3];

  ushort_t* Lpred = (ushort_t*)d_ws;                  // 4MB
  ushort_t* Rpred = Lpred + NMAT * 65536;             // 4MB
  ushort_t* Lgt   = Rpred + NMAT * 65536;             // 2MB
  ushort_t* Rgt   = Lgt + BATCH * 65536;              // 2MB
  float* FT    = (float*)(Rgt + BATCH * 65536);       // 32*2048 (grouped-T)
  float* GT    = FT + NMAT * NPTS;                    // 32*2048 (grouped-T)
  float* emd   = GT + NMAT * NPTS;                    // 1
  float* chamf = emd + 1;                             // 1

  const int initN = (NMAT + BATCH) * NPTS + 2;
  pack_kernel<<<(initN + 255) / 256, 256, 0, stream>>>(
      gt, p0, p1, Lpred, Rpred, Lgt, Rgt, emd, chamf);

  const int grid = NMAT * 32;   // 1024 blocks, 8 waves each, 64 rows/block
  // chamfer-fused first iteration (NF=2: extra accumulators)
  sink_kernel<1, 0, 0, 0, 2><<<grid, 512, 0, stream>>>(Lpred, Rpred, Lgt, Rgt, FT, GT, chamf, emd);
  sink_kernel<1, 1, 1, 0, 2><<<grid, 512, 0, stream>>>(Lpred, Rpred, Lgt, Rgt, FT, GT, chamf, emd);
  for (int it = 1; it < ITERS - 1; ++it) {
    sink_kernel<0, 1, 0, 0, 4><<<grid, 512, 0, stream>>>(Lpred, Rpred, Lgt, Rgt, FT, GT, chamf, emd);
    sink_kernel<0, 1, 1, 0, 4><<<grid, 512, 0, stream>>>(Lpred, Rpred, Lgt, Rgt, FT, GT, chamf, emd);
  }
  // final iteration: f-update, then g-update with fused EMD cost (NF=2)
  sink_kernel<0, 1, 0, 0, 4><<<grid, 512, 0, stream>>>(Lpred, Rpred, Lgt, Rgt, FT, GT, chamf, emd);
  sink_kernel<0, 1, 1, 1, 2><<<grid, 512, 0, stream>>>(Lpred, Rpred, Lgt, Rgt, FT, GT, chamf, emd);
  final_kernel<<<1, 64, 0, stream>>>(emd, chamf, (float*)d_out);
}

// Round 15
// 1066.728 us; speedup vs baseline: 2.3409x; 2.3409x over previous
//
#include <hip/hip_runtime.h>

#define BATCH 16
#define NPTS  2048
#define NMAT  32   // 16 batches x 2 preds
#define ITERS 20

typedef short bf16x8 __attribute__((ext_vector_type(8)));
typedef float f32x4 __attribute__((ext_vector_type(4)));
typedef unsigned short ushort_t;
typedef unsigned int uint_t;

// K = log2(e)/EPS, EPS = 0.05. Potentials pre-scaled: F = f*K (log2-domain).
// No LSE shift needed: terms 2^(pv - K*C) stay in fp32 range by ~80 bits.
constexpr float KSCALE = 28.853900817779268f;

__device__ __forceinline__ float fexp2(float x){ return __builtin_amdgcn_exp2f(x); }
__device__ __forceinline__ float flog2(float x){ return __builtin_amdgcn_logf(x); }
// sqrt(|x|): abs folds into v_sqrt_f32 as a free input modifier.
__device__ __forceinline__ float fsqrta(float x){ return __builtin_amdgcn_sqrtf(__builtin_fabsf(x)); }

__device__ __forceinline__ ushort_t bfr16(float x){
  uint_t u = __float_as_uint(x);
  return (ushort_t)((u + 0x7FFFu + ((u >> 16) & 1u)) >> 16);
}
__device__ __forceinline__ float bfrf(float x){
  return __uint_as_float(((uint_t)bfr16(x)) << 16);
}

// Per-point MFMA fragment encodings (27 used slots of K=32), bf16:
// per component c: L=[nh,nm,nl, 1,1,1, -2ah,-2ah,-2al], R=[1,1,1, nh,nm,nl, bh,bl,bh]
// sum_k L_k(p)*R_k(g) = |p|^2 + |g|^2 - 2(ah*bh+ah*bl+al*bh) ~= ||p-g||^2.
// Storage per cloud: 128 tiles x 1KB; lane l of tile t reads 16B at t*1024+l*16
// holding point (l&15)'s slots (l>>4)*8..+7 (A and B identical layout).
__device__ __forceinline__ void store_enc(ushort_t* base, int pt, const ushort_t* enc){
  ushort_t* p = base + (pt >> 4) * 512 + (pt & 15) * 8;
#pragma unroll
  for (int g = 0; g < 4; ++g){
    *reinterpret_cast<ushort4*>(p + g*128)     = make_ushort4(enc[g*8+0],enc[g*8+1],enc[g*8+2],enc[g*8+3]);
    *reinterpret_cast<ushort4*>(p + g*128 + 4) = make_ushort4(enc[g*8+4],enc[g*8+5],enc[g*8+6],enc[g*8+7]);
  }
}

__global__ void __launch_bounds__(256) pack_kernel(
    const float* __restrict__ gt, const float* __restrict__ p0, const float* __restrict__ p1,
    ushort_t* __restrict__ Lpred, ushort_t* __restrict__ Rpred,
    ushort_t* __restrict__ Lgt,   ushort_t* __restrict__ Rgt,
    float* __restrict__ emd, float* __restrict__ chamf)
{
  const int idx = blockIdx.x * 256 + threadIdx.x;
  const int totalPts = (NMAT + BATCH) * NPTS;
  if (idx < totalPts) {
    const int cl = idx >> 11, pt = idx & (NPTS - 1);
    const float* src; ushort_t *Lb, *Rb;
    if (cl < NMAT) {
      const int b = cl >> 1;
      src = ((cl & 1) ? p1 : p0) + (b * NPTS + pt) * 3;
      Lb = Lpred + cl * 65536; Rb = Rpred + cl * 65536;
    } else {
      const int b = cl - NMAT;
      src = gt + (b * NPTS + pt) * 3;
      Lb = Lgt + b * 65536; Rb = Rgt + b * 65536;
    }
    float L[32], R[32];
#pragma unroll
    for (int k = 27; k < 32; ++k){ L[k] = 0.f; R[k] = 0.f; }
#pragma unroll
    for (int c = 0; c < 3; ++c){
      const float v  = src[c];
      const float ah = bfrf(v), al = bfrf(v - ah);
      const float n2 = v * v;
      const float nh = bfrf(n2); const float r1 = n2 - nh;
      const float nm = bfrf(r1); const float nl = bfrf(r1 - nm);
      const int B0 = c * 9;
      L[B0+0]=nh;  L[B0+1]=nm;  L[B0+2]=nl;
      L[B0+3]=1.f; L[B0+4]=1.f; L[B0+5]=1.f;
      L[B0+6]=-2.f*ah; L[B0+7]=-2.f*ah; L[B0+8]=-2.f*al;
      R[B0+0]=1.f; R[B0+1]=1.f; R[B0+2]=1.f;
      R[B0+3]=nh;  R[B0+4]=nm;  R[B0+5]=nl;
      R[B0+6]=ah;  R[B0+7]=al;  R[B0+8]=ah;
    }
    ushort_t Le[32], Re[32];
#pragma unroll
    for (int k = 0; k < 32; ++k){ Le[k] = bfr16(L[k]); Re[k] = bfr16(R[k]); }
    store_enc(Lb, pt, Le);
    store_enc(Rb, pt, Re);
  } else if (idx == totalPts) {
    emd[0] = 0.f;
  } else if (idx == totalPts + 1) {
    chamf[0] = 0.f;
  }
}

// One Sinkhorn half-update over all 32 matrices via MFMA distance tiles.
// Grid = NMAT*32 (XCD-swizzled); block = 512 thr = 8 waves = 64 rows x 2048 cols.
// NF = A-fragments per wave (register-budget checked vs __launch_bounds__(512,8),
// i.e. 64 VGPRs):
//   NF=2: 32 rows x 512 cols/wave, ~45 VGPR  -> plain dispatches (37 of 41)
//   NF=1: 16 rows x 1024 cols/wave, ~34 VGPR -> CHAM/COST dispatches (extra accs)
//   (NF=4 needs ~70+ VGPR -> SPILLS at 8 waves/SIMD; proven 2.2x regression r14)
// Potentials in group-of-4 layout: pot[(t>>2)*64 + c*4 + (t&3)], point i=t*16+c.
// COST=1 (final g-update): T_j = sum_i 2^(F_i-K*C)*C fused; emd += 2^(G_j)*T_j.
template<int CHAM, int RPOT, int GSIDE, int COST, int NF>
__global__ void __launch_bounds__(512, 8) sink_kernel(
    const ushort_t* __restrict__ Lpred, const ushort_t* __restrict__ Rpred,
    const ushort_t* __restrict__ Lgt,   const ushort_t* __restrict__ Rgt,
    float* __restrict__ FT, float* __restrict__ GT,
    float* __restrict__ chamf, float* __restrict__ emd)
{
  constexpr int RWR  = NF * 16;          // rows per wave
  constexpr int RS   = 64 / RWR;         // row splits (2 or 4)
  constexpr int WCOL = 8 / RS;           // col splits (4 or 2)
  constexpr int G4N  = 2048 / WCOL / 64; // 4-tile groups per wave (8 or 16)

  // XCD-aware swizzle: each XCD gets a contiguous logical range (1024%8==0)
  const int bx0 = blockIdx.x;
  const int bx  = (bx0 & 7) * (NMAT * 32 / 8) + (bx0 >> 3);
  const int m   = bx >> 5;
  const int rg5 = bx & 31;
  const int b   = m >> 1;
  const int tid = threadIdx.x;
  const int l   = tid & 63;
  const int w   = __builtin_amdgcn_readfirstlane(tid >> 6);
  const int wr  = w / WCOL;
  const int wc  = w % WCOL;

  const ushort_t* A  = GSIDE ? (Lgt + b*65536)   : (Lpred + m*65536);
  const ushort_t* Bm = GSIDE ? (Rpred + m*65536) : (Rgt + b*65536);
  const float* pinT  = (GSIDE ? FT : GT) + m*NPTS;
  float*       poutT = (GSIDE ? GT : FT) + m*NPTS;

  __shared__ float ssum[8][64];
  __shared__ float sdm[8][64];   // chamfer mins OR cost T sums (never both)

  // A fragments: rows rg5*64 + wr*RWR + q*16 .. +15
  bf16x8 af[NF];
#pragma unroll
  for (int q = 0; q < NF; ++q)
    af[q] = *reinterpret_cast<const bf16x8*>(A + (rg5*4 + wr*NF + q)*512 + l*8);

  float s[NF][4], dmn[NF][4], t[NF][4];
#pragma unroll
  for (int q = 0; q < NF; ++q)
#pragma unroll
    for (int r = 0; r < 4; ++r){ s[q][r]=0.f; dmn[q][r]=1e30f; t[q][r]=0.f; }

  const f32x4 zz = {0.f,0.f,0.f,0.f};
  const ushort_t* Bu = Bm + wc * (G4N*4) * 512;   // wave-uniform base
  const int voff = l * 8;
  const float* PTu = pinT + (wc*G4N)*64 + (l & 15)*4;

#pragma unroll 2
  for (int g4 = 0; g4 < G4N; ++g4) {
    const ushort_t* Bg = Bu + g4 * 2048;
    float cpv[4];
    if (RPOT) {
      const float4 cp = *reinterpret_cast<const float4*>(PTu + g4*64);
      cpv[0]=cp.x; cpv[1]=cp.y; cpv[2]=cp.z; cpv[3]=cp.w;
    } else {
      cpv[0]=0.f; cpv[1]=0.f; cpv[2]=0.f; cpv[3]=0.f;
    }
#pragma unroll
    for (int tt = 0; tt < 4; ++tt) {
      const bf16x8 bf = *reinterpret_cast<const bf16x8*>(Bg + voff + tt*512);
      const float pv = cpv[tt];
#pragma unroll
      for (int q = 0; q < NF; ++q) {
        f32x4 d4 = __builtin_amdgcn_mfma_f32_16x16x32_bf16(af[q], bf, zz, 0, 0, 0);
#pragma unroll
        for (int r = 0; r < 4; ++r) {
          if (CHAM) dmn[q][r] = fminf(dmn[q][r], d4[r]);
          const float C = fsqrta(d4[r]);
          const float e = RPOT ? fmaf(-KSCALE, C, pv) : (-KSCALE * C);
          const float x = fexp2(e);
          s[q][r] += x;
          if (COST) t[q][r] = fmaf(x, C, t[q][r]);
        }
      }
    }
  }

  // reduce across the 16 col-lanes sharing each row
#pragma unroll
  for (int o = 1; o < 16; o <<= 1) {
#pragma unroll
    for (int q = 0; q < NF; ++q)
#pragma unroll
      for (int r = 0; r < 4; ++r) {
        s[q][r] += __shfl_xor(s[q][r], o);
        if (CHAM) dmn[q][r] = fminf(dmn[q][r], __shfl_xor(dmn[q][r], o));
        if (COST) t[q][r] += __shfl_xor(t[q][r], o);
      }
  }
  if ((l & 15) == 0) {
    const int g = l >> 4;
#pragma unroll
    for (int q = 0; q < NF; ++q)
#pragma unroll
      for (int r = 0; r < 4; ++r) {
        ssum[w][q*16 + g*4 + r] = s[q][r];
        if (CHAM) sdm[w][q*16 + g*4 + r] = dmn[q][r];
        if (COST) sdm[w][q*16 + g*4 + r] = t[q][r];
      }
  }
  __syncthreads();

  // wave 0: 64 lanes = 64 rows; combine col-split waves, finalize
  if (tid < 64) {
    const int wrr = tid / RWR;
    const int lr  = tid % RWR;
    float S = 0.f;
#pragma unroll
    for (int k = 0; k < WCOL; ++k) S += ssum[wrr*WCOL + k][lr];
    const float val = -11.0f - flog2(S);
    poutT[rg5*64 + (tid & 15)*4 + (tid >> 4)] = val;
    if (CHAM) {
      float dm = 1e30f;
#pragma unroll
      for (int k = 0; k < WCOL; ++k) dm = fminf(dm, sdm[wrr*WCOL + k][lr]);
#pragma unroll
      for (int o = 1; o < 64; o <<= 1) dm += __shfl_xor(dm, o);
      if (tid == 0) atomicAdd(chamf, dm);
    }
    if (COST) {
      float Ts = 0.f;
#pragma unroll
      for (int k = 0; k < WCOL; ++k) Ts += sdm[wrr*WCOL + k][lr];
      float cj = fexp2(val) * Ts;
#pragma unroll
      for (int o = 1; o < 64; o <<= 1) cj += __shfl_xor(cj, o);
      if (tid == 0) atomicAdd(emd, cj);
    }
  }
}

__global__ void final_kernel(const float* __restrict__ emd,
                             const float* __restrict__ chamf,
                             float* __restrict__ out)
{
  if (blockIdx.x == 0 && threadIdx.x == 0) {
    out[0] = chamf[0] / (float)(BATCH * NPTS) + emd[0] / (float)BATCH;
  }
}

extern "C" void kernel_launch(void* const* d_in, const int* in_sizes, int n_in,
                              void* d_out, int out_size, void* d_ws, size_t ws_size,
                              hipStream_t stream) {
  (void)in_sizes; (void)n_in; (void)out_size; (void)ws_size;
  const float* gt = (const float*)d_in[0];
  const float* p0 = (const float*)d_in[2];
  const float* p1 = (const float*)d_in[3];

  ushort_t* Lpred = (ushort_t*)d_ws;                  // 4MB
  ushort_t* Rpred = Lpred + NMAT * 65536;             // 4MB
  ushort_t* Lgt   = Rpred + NMAT * 65536;             // 2MB
  ushort_t* Rgt   = Lgt + BATCH * 65536;              // 2MB
  float* FT    = (float*)(Rgt + BATCH * 65536);       // 32*2048 (grouped-T)
  float* GT    = FT + NMAT * NPTS;                    // 32*2048 (grouped-T)
  float* emd   = GT + NMAT * NPTS;                    // 1
  float* chamf = emd + 1;                             // 1

  const int initN = (NMAT + BATCH) * NPTS + 2;
  pack_kernel<<<(initN + 255) / 256, 256, 0, stream>>>(
      gt, p0, p1, Lpred, Rpred, Lgt, Rgt, emd, chamf);

  const int grid = NMAT * 32;   // 1024 blocks, 8 waves each, 64 rows/block
  // chamfer-fused first iteration: NF=1 (extra accumulators need the headroom)
  sink_kernel<1, 0, 0, 0, 1><<<grid, 512, 0, stream>>>(Lpred, Rpred, Lgt, Rgt, FT, GT, chamf, emd);
  sink_kernel<1, 1, 1, 0, 1><<<grid, 512, 0, stream>>>(Lpred, Rpred, Lgt, Rgt, FT, GT, chamf, emd);
  for (int it = 1; it < ITERS - 1; ++it) {
    sink_kernel<0, 1, 0, 0, 2><<<grid, 512, 0, stream>>>(Lpred, Rpred, Lgt, Rgt, FT, GT, chamf, emd);
    sink_kernel<0, 1, 1, 0, 2><<<grid, 512, 0, stream>>>(Lpred, Rpred, Lgt, Rgt, FT, GT, chamf, emd);
  }
  // final iteration: f-update (plain NF=2), then g-update with fused EMD cost (NF=1)
  sink_kernel<0, 1, 0, 0, 2><<<grid, 512, 0, stream>>>(Lpred, Rpred, Lgt, Rgt, FT, GT, chamf, emd);
  sink_kernel<0, 1, 1, 1, 1><<<grid, 512, 0, stream>>>(Lpred, Rpred, Lgt, Rgt, FT, GT, chamf, emd);
  final_kernel<<<1, 64, 0, stream>>>(emd, chamf, (float*)d_out);
}